// Round 10
// baseline (119.506 us; speedup 1.0000x reference)
//
#include <hip/hip_runtime.h>
#include <math.h>

#define A_N   8732
#define A_PAD 8736            // A_N rounded up to 8 (u16 pad, zeros)
#define C_N   81
#define B_N   32
#define NCLS  80
#define NTASK (B_N * NCLS)
#define TOPK  100
#define NTHR  256             // transpose / fallback block size
#define WAVE  64
#define CAND  384
#define TA    64
#define NV4K  (A_PAD / 8)     // 1092 uint4 (8 u16 keys each) per key row
#define KPTW  18              // ceil(NV4K / 64)
#define K0    0xBE00u         // k16 >= K0  <=>  x >= 0.125
#define THR_LOGIT (-0.8472978603872034)

// Monotone map: float bits -> unsigned, order-preserving. 0 = invalid sentinel.
__device__ __forceinline__ unsigned mapf(float x) {
    unsigned b = __float_as_uint(x);
    return b ^ ((b & 0x80000000u) ? 0xFFFFFFFFu : 0x80000000u);
}
__device__ __forceinline__ float unmapf(unsigned u) {
    unsigned b = (u & 0x80000000u) ? (u ^ 0x80000000u) : ~u;
    return __uint_as_float(b);
}

// Exact f64 decode (reference op order) from raw regression/prior values.
__device__ __forceinline__ void dec64(const float4 r4, const float4 p4,
                                      double* bx, double* area) {
    double ty = (double)r4.x / 10.0, tx = (double)r4.y / 10.0;
    double th = (double)r4.z / 5.0,  tw = (double)r4.w / 5.0;
    double cy = ty * (double)p4.z + (double)p4.x;
    double cx = tx * (double)p4.w + (double)p4.y;
    double hh = exp(th) * (double)p4.z;
    double ww = exp(tw) * (double)p4.w;
    bx[0] = cy - hh / 2.0; bx[1] = cx - ww / 2.0;
    bx[2] = cy + hh / 2.0; bx[3] = cx + ww / 2.0;
    double e0 = bx[2] - bx[0]; if (e0 < 0.0) e0 = 0.0;
    double e1 = bx[3] - bx[1]; if (e1 < 0.0) e1 = 0.0;
    *area = e0 * e1;
}

// ---- Kernel T: coalesced logits read, u16 keys transposed to (B, 80, A_PAD) ----
__global__ __launch_bounds__(NTHR) void key_transpose_kernel(
    const float* __restrict__ logits,          // (B, A, 81)
    unsigned short* __restrict__ keys)         // (B, 80, A_PAD) u16
{
    __shared__ unsigned short tile[NCLS][TA + 2];   // 80 x 66 u16 = 10.3 KB
    const int NT = (A_N + TA - 1) / TA;             // 137
    const int b  = blockIdx.x / NT;
    const int t0 = blockIdx.x % NT;
    const int a0 = t0 * TA;
    const int an = min(TA, A_N - a0);
    const int tid = threadIdx.x;

    const float* src = logits + ((size_t)b * A_N + a0) * C_N;

    if (an == TA) {
        const float4* src4 = (const float4*)src;
        const int total4 = TA * C_N / 4;            // 1296
        for (int i = tid; i < total4; i += NTHR) {
            float4 v = src4[i];
            int base = 4 * i;
            int r  = base / C_N;
            int ch = base - r * C_N;
            float xs[4] = { v.x, v.y, v.z, v.w };
            #pragma unroll
            for (int k = 0; k < 4; ++k) {
                if (ch > 0)
                    tile[ch - 1][r] = (unsigned short)
                        (((double)xs[k] > THR_LOGIT) ? (mapf(xs[k]) >> 16) : 0u);
                if (++ch == C_N) { ch = 0; ++r; }
            }
        }
        __syncthreads();
        for (int i = tid; i < NCLS * 8; i += NTHR) {
            int row = i >> 3, j = i & 7;
            const unsigned* t32 = (const unsigned*)&tile[row][8 * j];
            uint4 w;
            w.x = t32[0]; w.y = t32[1]; w.z = t32[2]; w.w = t32[3];
            *(uint4*)(keys + ((size_t)(b * NCLS + row)) * A_PAD + a0 + 8 * j) = w;
        }
    } else {
        const int total = an * C_N;
        for (int i = tid; i < total; i += NTHR) {
            int r = i / C_N, ch = i - r * C_N;
            float x = src[i];
            if (ch > 0)
                tile[ch - 1][r] = (unsigned short)
                    (((double)x > THR_LOGIT) ? (mapf(x) >> 16) : 0u);
        }
        __syncthreads();
        for (int i = tid; i < NCLS * TA; i += NTHR) {
            int row = i / TA, col = i - row * TA;
            int a = a0 + col;
            if (a < A_PAD)
                keys[((size_t)(b * NCLS + row)) * A_PAD + a] =
                    (col < an) ? tile[row][col] : (unsigned short)0;
        }
    }
}

// ---- Kernel W: ONE WAVE per task; zero barriers; register NMS scan ----
__global__ __launch_bounds__(WAVE) void ssd_nms_wave(
    const float* __restrict__ logits,
    const unsigned short* __restrict__ keys,
    const float* __restrict__ boxreg,
    const float* __restrict__ priors,
    float* __restrict__ out)
{
    const int task = blockIdx.x;
    const int b = task / NCLS;
    const int c = task % NCLS;
    const int l = threadIdx.x;          // lane 0..63

    __shared__ unsigned hist[128];
    __shared__ unsigned candi[CAND];
    __shared__ unsigned long long cand[CAND];
    __shared__ unsigned long long ssel[TOPK];
    __shared__ float4 fbox4[TOPK];
    __shared__ float farea[TOPK];
    __shared__ int sanchor[TOPK];

    const float* lg = logits + ((size_t)b * A_N * C_N) + (c + 1);
    const uint4* ksrc = (const uint4*)(keys + (size_t)task * A_PAD);
    const float4* breg4 = (const float4*)(boxreg + (size_t)b * A_N * 4);
    const float4* pri4  = (const float4*)priors;

    // ---- init LDS (single wave: DS ops are in program order, no barriers)
    hist[l] = 0; hist[WAVE + l] = 0;
    ssel[l] = 0ull;
    if (l < TOPK - WAVE) ssel[WAVE + l] = 0ull;

    // ---- Pass A: 128-bin histogram of keys >= K0
    for (int j = 0; j < KPTW; ++j) {
        int i = l + j * WAVE;
        if (i < NV4K) {
            uint4 v = ksrc[i];
            unsigned k;
            k = v.x & 0xFFFFu; if (k >= K0) { unsigned bn = (k - K0) >> 4; if (bn > 127u) bn = 127u; atomicAdd(&hist[bn], 1u); }
            k = v.x >> 16;     if (k >= K0) { unsigned bn = (k - K0) >> 4; if (bn > 127u) bn = 127u; atomicAdd(&hist[bn], 1u); }
            k = v.y & 0xFFFFu; if (k >= K0) { unsigned bn = (k - K0) >> 4; if (bn > 127u) bn = 127u; atomicAdd(&hist[bn], 1u); }
            k = v.y >> 16;     if (k >= K0) { unsigned bn = (k - K0) >> 4; if (bn > 127u) bn = 127u; atomicAdd(&hist[bn], 1u); }
            k = v.z & 0xFFFFu; if (k >= K0) { unsigned bn = (k - K0) >> 4; if (bn > 127u) bn = 127u; atomicAdd(&hist[bn], 1u); }
            k = v.z >> 16;     if (k >= K0) { unsigned bn = (k - K0) >> 4; if (bn > 127u) bn = 127u; atomicAdd(&hist[bn], 1u); }
            k = v.w & 0xFFFFu; if (k >= K0) { unsigned bn = (k - K0) >> 4; if (bn > 127u) bn = 127u; atomicAdd(&hist[bn], 1u); }
            k = v.w >> 16;     if (k >= K0) { unsigned bn = (k - K0) >> 4; if (bn > 127u) bn = 127u; atomicAdd(&hist[bn], 1u); }
        }
    }

    // ---- cutoff: shfl suffix scan over 128 bins (lane l: bins l and 64+l)
    unsigned cut16 = 1u;
    {
        unsigned sL = hist[l], sH = hist[WAVE + l];
        unsigned inclH = sH, inclL = sL;
        #pragma unroll
        for (int off = 1; off < 64; off <<= 1) {
            unsigned t = __shfl_down(inclH, off); if (l + off < 64) inclH += t;
        }
        #pragma unroll
        for (int off = 1; off < 64; off <<= 1) {
            unsigned t = __shfl_down(inclL, off); if (l + off < 64) inclL += t;
        }
        unsigned TH = __shfl(inclH, 0);
        unsigned SH = inclH;            // count of keys in bins >= 64+l
        unsigned SL = inclL + TH;       // count of keys in bins >= l
        unsigned T  = __shfl(SL, 0);    // total keys >= K0

        if (T >= TOPK) {
            bool crH = (SH >= TOPK) && (SH - sH < TOPK);
            bool crL = (SL >= TOPK) && (SL - sL < TOPK);
            unsigned myCut = crH ? (K0 + ((unsigned)(WAVE + l) << 4))
                                 : (K0 + ((unsigned)l << 4));
            unsigned long long cm = __ballot(crH || crL);
            cut16 = __shfl(myCut, (int)(__ffsll((long long)cm) - 1));
        } else {
            // rare: coarse bins (width 256) over [0x4000, K0)
            hist[l] = 0; hist[WAVE + l] = 0;
            for (int j = 0; j < KPTW; ++j) {
                int i = l + j * WAVE;
                if (i < NV4K) {
                    uint4 v = ksrc[i];
                    unsigned k;
                    k = v.x & 0xFFFFu; if (k >= 0x4000u && k < K0) atomicAdd(&hist[(k - 0x4000u) >> 8], 1u);
                    k = v.x >> 16;     if (k >= 0x4000u && k < K0) atomicAdd(&hist[(k - 0x4000u) >> 8], 1u);
                    k = v.y & 0xFFFFu; if (k >= 0x4000u && k < K0) atomicAdd(&hist[(k - 0x4000u) >> 8], 1u);
                    k = v.y >> 16;     if (k >= 0x4000u && k < K0) atomicAdd(&hist[(k - 0x4000u) >> 8], 1u);
                    k = v.z & 0xFFFFu; if (k >= 0x4000u && k < K0) atomicAdd(&hist[(k - 0x4000u) >> 8], 1u);
                    k = v.z >> 16;     if (k >= 0x4000u && k < K0) atomicAdd(&hist[(k - 0x4000u) >> 8], 1u);
                    k = v.w & 0xFFFFu; if (k >= 0x4000u && k < K0) atomicAdd(&hist[(k - 0x4000u) >> 8], 1u);
                    k = v.w >> 16;     if (k >= 0x4000u && k < K0) atomicAdd(&hist[(k - 0x4000u) >> 8], 1u);
                }
            }
            unsigned sL2 = hist[l], sH2 = hist[WAVE + l];
            unsigned iH = sH2, iL = sL2;
            #pragma unroll
            for (int off = 1; off < 64; off <<= 1) {
                unsigned t = __shfl_down(iH, off); if (l + off < 64) iH += t;
            }
            #pragma unroll
            for (int off = 1; off < 64; off <<= 1) {
                unsigned t = __shfl_down(iL, off); if (l + off < 64) iL += t;
            }
            unsigned TH2 = __shfl(iH, 0);
            unsigned SH2 = iH, SL2 = iL + TH2;
            unsigned need = TOPK - T;
            bool crH = (SH2 >= need) && (SH2 - sH2 < need);
            bool crL = (SL2 >= need) && (SL2 - sL2 < need);
            unsigned myCut = crH ? (0x4000u + ((unsigned)(WAVE + l) << 8))
                                 : (0x4000u + ((unsigned)l << 8));
            unsigned long long cm = __ballot(crH || crL);
            if (cm) cut16 = __shfl(myCut, (int)(__ffsll((long long)cm) - 1));
        }
    }

    // ---- gather candidate indices via ballot append (no atomics)
    int cnt = 0;
    auto gstep = [&](unsigned kk, int idx) {
        bool pr = (kk >= cut16);
        unsigned long long mk = __ballot(pr);
        if (pr) {
            int pos = cnt + (int)__popcll(mk & ((1ull << l) - 1ull));
            if (pos < CAND) candi[pos] = (unsigned)idx;
        }
        cnt += (int)__popcll(mk);
    };
    for (int j = 0; j < KPTW; ++j) {
        int i = l + j * WAVE;
        uint4 v = (i < NV4K) ? ksrc[i] : make_uint4(0u, 0u, 0u, 0u);
        int a8 = 8 * i;
        gstep(v.x & 0xFFFFu, a8 + 0); gstep(v.x >> 16, a8 + 1);
        gstep(v.y & 0xFFFFu, a8 + 2); gstep(v.y >> 16, a8 + 3);
        gstep(v.z & 0xFFFFu, a8 + 4); gstep(v.z >> 16, a8 + 5);
        gstep(v.w & 0xFFFFu, a8 + 6); gstep(v.w >> 16, a8 + 7);
    }
    const int M  = min(cnt, CAND);
    const int Mr = (M + 7) & ~7;
    if (l < Mr - M) cand[M + l] = 0ull;     // zero the pad slots

    // ---- rebuild full-precision keys for the ~M candidates (L2/L3 hits)
    #pragma unroll
    for (int k = 0; k < CAND / WAVE; ++k) {
        int i = l + k * WAVE;
        if (i < M) {
            unsigned a = candi[i];
            float x = lg[(size_t)a * C_N];
            cand[i] = ((unsigned long long)mapf(x) << 32) | (unsigned)(~a);
        }
    }

    // ---- exact rank via all-pairs (broadcast LDS reads)
    {
        unsigned long long mk2[CAND / WAVE];
        int rk[CAND / WAVE];
        #pragma unroll
        for (int k = 0; k < CAND / WAVE; ++k) {
            int i = l + k * WAVE;
            mk2[k] = (i < Mr) ? cand[i] : 0ull;
            rk[k] = 0;
        }
        for (int j = 0; j < Mr; ++j) {
            unsigned long long cj = cand[j];
            #pragma unroll
            for (int k = 0; k < CAND / WAVE; ++k)
                if (k * WAVE < Mr)                    // uniform, loop-invariant
                    rk[k] += (cj > mk2[k]) ? 1 : 0;
        }
        #pragma unroll
        for (int k = 0; k < CAND / WAVE; ++k)
            if (mk2[k] != 0ull && rk[k] < TOPK) ssel[rk[k]] = mk2[k];
    }

    // ---- decode: lane l owns slots l and 64+l (f32, hw exp)
    unsigned long long keyA = ssel[l];
    unsigned long long keyB = (l < TOPK - WAVE) ? ssel[WAVE + l] : 0ull;
    float A0 = 0, A1 = 0, A2 = 0, A3 = 0, arA = 0, scA = 0; int aA = 0;
    float B0 = 0, B1 = 0, B2 = 0, B3 = 0, arB = 0, scB = 0; int aB = 0;
    if (keyA) {
        aA = (int)(~(unsigned)keyA);
        float x = unmapf((unsigned)(keyA >> 32));
        scA = 1.0f / (1.0f + __expf(-x));
        float4 r4 = breg4[aA], p4 = pri4[aA];
        float cy = r4.x * 0.1f * p4.z + p4.x;
        float cx = r4.y * 0.1f * p4.w + p4.y;
        float hh = __expf(r4.z * 0.2f) * p4.z;
        float ww = __expf(r4.w * 0.2f) * p4.w;
        A0 = cy - hh * 0.5f; A1 = cx - ww * 0.5f;
        A2 = cy + hh * 0.5f; A3 = cx + ww * 0.5f;
        arA = fmaxf(A2 - A0, 0.f) * fmaxf(A3 - A1, 0.f);
    }
    fbox4[l] = make_float4(A0, A1, A2, A3); farea[l] = arA; sanchor[l] = aA;
    if (l < TOPK - WAVE) {
        if (keyB) {
            aB = (int)(~(unsigned)keyB);
            float x = unmapf((unsigned)(keyB >> 32));
            scB = 1.0f / (1.0f + __expf(-x));
            float4 r4 = breg4[aB], p4 = pri4[aB];
            float cy = r4.x * 0.1f * p4.z + p4.x;
            float cx = r4.y * 0.1f * p4.w + p4.y;
            float hh = __expf(r4.z * 0.2f) * p4.z;
            float ww = __expf(r4.w * 0.2f) * p4.w;
            B0 = cy - hh * 0.5f; B1 = cx - ww * 0.5f;
            B2 = cy + hh * 0.5f; B3 = cx + ww * 0.5f;
            arB = fmaxf(B2 - B0, 0.f) * fmaxf(B3 - B1, 0.f);
        }
        fbox4[WAVE + l] = make_float4(B0, B1, B2, B3);
        farea[WAVE + l] = arB; sanchor[WAVE + l] = aB;
    }
    const unsigned long long v0 = __ballot(keyA != 0ull);
    const unsigned long long v1 = __ballot(l < TOPK - WAVE && keyB != 0ull);

    // ---- suppression row masks in registers: lane l -> rows l and 99-l (l<50)
    auto pairSup = [&](float i0, float i1, float i2, float i3, float ia,
                       int ai, int j) -> bool {
        float4 bj = fbox4[j]; float aj = farea[j];
        float tl0 = fmaxf(i0, bj.x), tl1 = fmaxf(i1, bj.y);
        float br0 = fminf(i2, bj.z), br1 = fminf(i3, bj.w);
        float wh0 = fmaxf(br0 - tl0, 0.f), wh1 = fmaxf(br1 - tl1, 0.f);
        float inter = wh0 * wh1;
        float denom = (ia + aj) - inter;
        bool sup = inter > 0.601f * denom;
        bool amb = !sup && (inter > 0.599f * denom) && (inter > 0.f);
        if (amb) {   // rare: exact f64 from raw global values
            int ja = sanchor[j];
            double bi[4], bj_[4], ai_, aj_;
            dec64(breg4[ai], pri4[ai], bi, &ai_);
            dec64(breg4[ja], pri4[ja], bj_, &aj_);
            double t0 = fmax(bi[0], bj_[0]), t1 = fmax(bi[1], bj_[1]);
            double b0 = fmin(bi[2], bj_[2]), b1 = fmin(bi[3], bj_[3]);
            double w0 = b0 - t0; if (w0 < 0.0) w0 = 0.0;
            double w1 = b1 - t1; if (w1 < 0.0) w1 = 0.0;
            double interd = w0 * w1;
            sup = interd > 0.6 * (((ai_ + aj_) - interd) + 1e-9);
        }
        return sup;
    };

    unsigned long long mA0 = 0, mA1 = 0, mB0 = 0, mB1 = 0;
    if (l < 50) {
        // row A = l (box in registers)
        for (int j = l + 1; j < TOPK; ++j) {
            if (pairSup(A0, A1, A2, A3, arA, aA, j)) {
                if (j < 64) mA0 |= 1ull << j; else mA1 |= 1ull << (j - 64);
            }
        }
        // row B = 99 - l
        int rB = 99 - l;
        float4 bi = fbox4[rB]; float ai = farea[rB]; int aiB = sanchor[rB];
        for (int j = rB + 1; j < TOPK; ++j) {
            if (pairSup(bi.x, bi.y, bi.z, bi.w, ai, aiB, j)) {
                if (j < 64) mB0 |= 1ull << j; else mB1 |= 1ull << (j - 64);
            }
        }
    }

    // ---- greedy scan, fully in registers via shfl broadcast (uniform)
    unsigned long long kp0 = ~0ull, kp1 = (1ull << (TOPK - WAVE)) - 1ull;
    for (int i = 0; i < TOPK; ++i) {
        bool low = (i < 50);
        int src = low ? i : 99 - i;
        unsigned long long m0 = low ? __shfl(mA0, src) : __shfl(mB0, src);
        unsigned long long m1 = low ? __shfl(mA1, src) : __shfl(mB1, src);
        bool kb = (i < 64) ? ((kp0 >> i) & 1ull) : ((kp1 >> (i - 64)) & 1ull);
        bool vb = (i < 64) ? ((v0 >> i) & 1ull) : ((v1 >> (i - 64)) & 1ull);
        if (kb && vb) { kp0 &= ~m0; kp1 &= ~m1; }
    }

    // ---- write: lane l writes slots l and 64+l from registers
    {
        bool keepA = ((kp0 >> l) & 1ull) && (keyA != 0ull);
        size_t baseA = ((size_t)task * TOPK + l) * 5;
        out[baseA + 0] = keepA ? A0 : 0.0f;
        out[baseA + 1] = keepA ? A1 : 0.0f;
        out[baseA + 2] = keepA ? A2 : 0.0f;
        out[baseA + 3] = keepA ? A3 : 0.0f;
        out[baseA + 4] = keepA ? scA : 0.0f;
        if (l < TOPK - WAVE) {
            bool keepB = ((kp1 >> l) & 1ull) && (keyB != 0ull);
            size_t baseB = ((size_t)task * TOPK + WAVE + l) * 5;
            out[baseB + 0] = keepB ? B0 : 0.0f;
            out[baseB + 1] = keepB ? B1 : 0.0f;
            out[baseB + 2] = keepB ? B2 : 0.0f;
            out[baseB + 3] = keepB ? B3 : 0.0f;
            out[baseB + 4] = keepB ? scB : 0.0f;
        }
    }
}

// ---- Fallback (ws too small): R9's 256-thread strided version ----
__global__ __launch_bounds__(NTHR) void ssd_nms_fallback(
    const float* __restrict__ logits,
    const float* __restrict__ boxreg,
    const float* __restrict__ priors,
    float* __restrict__ out)
{
    const int task = blockIdx.x;
    const int b = task / NCLS;
    const int c = task % NCLS;
    const int tid = threadIdx.x;

    __shared__ unsigned hist[2048];
    __shared__ unsigned wt4[4];
    __shared__ unsigned long long cand[CAND];
    __shared__ unsigned long long ssel[TOPK];
    __shared__ float fb0[TOPK], fb1[TOPK], fb2[TOPK], fb3[TOPK];
    __shared__ float farea[TOPK], fscore[TOPK];
    __shared__ float4 rbox[TOPK], pbox[TOPK];
    __shared__ int svalid[TOPK];
    __shared__ unsigned long long supmask[TOPK][2];
    __shared__ unsigned long long keepw[2];
    __shared__ int scal[2];

    const float* lg = logits + ((size_t)b * A_N * C_N) + (c + 1);

    for (int k = tid; k < 2048; k += NTHR) hist[k] = 0;
    for (int i = tid; i < CAND; i += NTHR) cand[i] = 0ull;
    if (tid < TOPK) ssel[tid] = 0ull;
    if (tid == 0) { scal[0] = 0; scal[1] = 1; }
    __syncthreads();

    for (int a = tid; a < A_N; a += NTHR) {
        float x = lg[(size_t)a * C_N];
        if ((double)x > THR_LOGIT) atomicAdd(&hist[mapf(x) >> 21], 1u);
    }
    __syncthreads();
    {
        unsigned s = 0;
        #pragma unroll
        for (int k = 0; k < 8; ++k) s += hist[tid * 8 + k];
        unsigned incl = s;
        int lane = tid & 63;
        #pragma unroll
        for (int off = 1; off < 64; off <<= 1) {
            unsigned v = __shfl_down(incl, off);
            if (lane + off < 64) incl += v;
        }
        if (lane == 0) wt4[tid >> 6] = incl;
        __syncthreads();
        unsigned hi = 0;
        #pragma unroll
        for (int w = 0; w < 4; ++w) if (w > (tid >> 6)) hi += wt4[w];
        unsigned excl = hi + (incl - s);
        if (excl < TOPK && excl + s >= TOPK) {
            unsigned running = excl;
            #pragma unroll
            for (int k = 7; k >= 0; --k) {
                running += hist[tid * 8 + k];
                if (running >= TOPK) { scal[1] = (int)(((unsigned)(tid * 8 + k)) << 21); break; }
            }
        }
    }
    __syncthreads();
    const unsigned cutoff = (unsigned)scal[1];

    for (int a = tid; a < A_N; a += NTHR) {
        float x = lg[(size_t)a * C_N];
        if ((double)x > THR_LOGIT) {
            unsigned u = mapf(x);
            if (u >= cutoff) {
                int p = atomicAdd(&scal[0], 1);
                if (p < CAND) cand[p] = ((unsigned long long)u << 32) | (unsigned)(~(unsigned)a);
            }
        }
    }
    __syncthreads();
    const int M = min(scal[0], CAND);
    {
        int Mr = (M + 7) & ~7;
        for (int i = tid; i < Mr; i += NTHR) {
            unsigned long long mykey = cand[i];
            int rank = 0;
            for (int j = 0; j < Mr; ++j) rank += (cand[j] > mykey) ? 1 : 0;
            if (mykey != 0ull && rank < TOPK) ssel[rank] = mykey;
        }
    }
    __syncthreads();
    if (tid < TOPK) {
        unsigned long long key = ssel[tid];
        int valid = (key != 0ull);
        float b0 = 0, b1 = 0, b2 = 0, b3 = 0, area = 0, sc = 0;
        float4 r4 = make_float4(0.f,0.f,0.f,0.f), p4 = r4;
        if (valid) {
            int a = (int)(~(unsigned)key);
            float x = unmapf((unsigned)(key >> 32));
            sc = 1.0f / (1.0f + __expf(-x));
            r4 = *(const float4*)(boxreg + ((size_t)b * A_N + a) * 4);
            p4 = *(const float4*)(priors + (size_t)a * 4);
            float cy = r4.x * 0.1f * p4.z + p4.x;
            float cx = r4.y * 0.1f * p4.w + p4.y;
            float hh = __expf(r4.z * 0.2f) * p4.z;
            float ww = __expf(r4.w * 0.2f) * p4.w;
            b0 = cy - hh * 0.5f; b1 = cx - ww * 0.5f;
            b2 = cy + hh * 0.5f; b3 = cx + ww * 0.5f;
            area = fmaxf(b2 - b0, 0.f) * fmaxf(b3 - b1, 0.f);
        }
        fb0[tid]=b0; fb1[tid]=b1; fb2[tid]=b2; fb3[tid]=b3;
        farea[tid]=area; fscore[tid]=sc; rbox[tid]=r4; pbox[tid]=p4; svalid[tid]=valid;
    }
    __syncthreads();
    if (tid < 2 * TOPK) {
        int i = tid >> 1, w = tid & 1;
        unsigned long long m = 0;
        if (svalid[i]) {
            float i0=fb0[i], i1=fb1[i], i2=fb2[i], i3=fb3[i], ia=farea[i];
            int jbase = w * 64, jend = min(jbase + 64, TOPK);
            int jstart = (jbase > i + 1) ? jbase : (i + 1);
            for (int j = jstart; j < jend; ++j) {
                float tl0=fmaxf(i0,fb0[j]), tl1=fmaxf(i1,fb1[j]);
                float br0=fminf(i2,fb2[j]), br1=fminf(i3,fb3[j]);
                float wh0=fmaxf(br0-tl0,0.f), wh1=fmaxf(br1-tl1,0.f);
                float inter=wh0*wh1, denom=(ia+farea[j])-inter;
                bool sup = inter > 0.601f*denom;
                bool amb = !sup && (inter > 0.599f*denom) && (inter > 0.f);
                if (__any(amb)) {
                    if (amb) {
                        double bi[4], bj[4], ai, aj;
                        dec64(rbox[i], pbox[i], bi, &ai);
                        dec64(rbox[j], pbox[j], bj, &aj);
                        double wh0d = fmin(bi[2],bj[2]) - fmax(bi[0],bj[0]); if (wh0d<0) wh0d=0;
                        double wh1d = fmin(bi[3],bj[3]) - fmax(bi[1],bj[1]); if (wh1d<0) wh1d=0;
                        double interd = wh0d*wh1d;
                        sup = interd > 0.6 * (((ai+aj)-interd)+1e-9);
                    }
                }
                if (sup) m |= 1ull << (j - jbase);
            }
        }
        supmask[i][w] = m;
    }
    __syncthreads();
    if (tid == 0) {
        unsigned long long kp0 = ~0ull, kp1 = ~0ull;
        for (int i = 0; i < TOPK; ++i) {
            bool kb = (i < 64) ? ((kp0 >> i) & 1ull) : ((kp1 >> (i - 64)) & 1ull);
            if (kb && svalid[i]) { kp0 &= ~supmask[i][0]; kp1 &= ~supmask[i][1]; }
        }
        keepw[0] = kp0; keepw[1] = kp1;
    }
    __syncthreads();
    if (tid < TOPK) {
        bool kb = (tid < 64) ? ((keepw[0] >> tid) & 1ull)
                             : ((keepw[1] >> (tid - 64)) & 1ull);
        bool kp = kb && (svalid[tid] != 0);
        size_t base = ((size_t)task * TOPK + tid) * 5;
        out[base + 0] = kp ? fb0[tid] : 0.0f;
        out[base + 1] = kp ? fb1[tid] : 0.0f;
        out[base + 2] = kp ? fb2[tid] : 0.0f;
        out[base + 3] = kp ? fb3[tid] : 0.0f;
        out[base + 4] = kp ? fscore[tid] : 0.0f;
    }
}

extern "C" void kernel_launch(void* const* d_in, const int* in_sizes, int n_in,
                              void* d_out, int out_size, void* d_ws, size_t ws_size,
                              hipStream_t stream) {
    const float* logits = (const float*)d_in[0];
    const float* boxreg = (const float*)d_in[1];
    const float* priors = (const float*)d_in[2];
    float* out = (float*)d_out;

    const size_t keys_bytes = (size_t)NTASK * A_PAD * sizeof(unsigned short); // 44.73 MB
    if (ws_size >= keys_bytes) {
        unsigned short* keysw = (unsigned short*)d_ws;
        const int NT = (A_N + TA - 1) / TA;
        key_transpose_kernel<<<dim3(B_N * NT), dim3(NTHR), 0, stream>>>(logits, keysw);
        ssd_nms_wave<<<dim3(NTASK), dim3(WAVE), 0, stream>>>(
            logits, keysw, boxreg, priors, out);
    } else {
        ssd_nms_fallback<<<dim3(NTASK), dim3(NTHR), 0, stream>>>(
            logits, boxreg, priors, out);
    }
}